// Round 1
// baseline (2148.712 us; speedup 1.0000x reference)
//
#include <hip/hip_runtime.h>

#define NB   4
#define NN1  8192
#define TT   15
#define NN2  4096
#define KCH  12
#define GG1  64
#define GG2  32
#define NCLS 6
#define EE1  131072
#define EE2  65536

// ---------------- degree / norm ----------------
__global__ void k_deg(const int* __restrict__ ei, const float* __restrict__ w,
                      float* __restrict__ deg, int E) {
    int e = blockIdx.x * 256 + threadIdx.x;
    if (e < E) atomicAdd(&deg[ei[E + e]], w[e]);   // segment_sum over dst
}

__global__ void k_norm(const int* __restrict__ ei, const float* __restrict__ w,
                       const float* __restrict__ deg, float* __restrict__ nrm, int E) {
    int e = blockIdx.x * 256 + threadIdx.x;
    if (e < E) {
        float ds = deg[ei[e]], dd = deg[ei[E + e]];
        float is = ds > 0.f ? 1.f / sqrtf(ds) : 0.f;
        float id = dd > 0.f ? 1.f / sqrtf(dd) : 0.f;
        nrm[e] = -w[e] * is * id;                  // L_hat = -D^-1/2 A D^-1/2
    }
}

// ---------------- build h0: x (B,N1,T) -> (N1, T*4[pad 64]) ----------------
__global__ void k_build_h0(const float* __restrict__ x, float* __restrict__ h0) {
    int idx = blockIdx.x * 256 + threadIdx.x;
    if (idx < NN1 * 60) {
        int n = idx / 60, r = idx - n * 60;
        int t = r >> 2, b = r & 3;
        h0[n * 64 + r] = x[(b * NN1 + n) * TT + t];
    }
}

// ---------------- propagation: S[dst] += norm * h[src] ----------------
template <int D, int SD, int LOG2DP>
__global__ void k_prop(const float* __restrict__ h, float* __restrict__ S,
                       const int* __restrict__ ei, const float* __restrict__ nrm, int E) {
    int tid = blockIdx.x * 256 + threadIdx.x;
    int e = tid >> LOG2DP, j = tid & ((1 << LOG2DP) - 1);
    if (e < E && j < D) {
        int s = ei[e], d = ei[E + e];
        atomicAdd(&S[d * SD + j], nrm[e] * h[s * SD + j]);
    }
}

// ---------------- T_next = 2*S - T_prev; T_prev <- 0 (becomes next S buffer) ----------------
__global__ void k_combine(float4* __restrict__ S, float4* __restrict__ P, int n4) {
    int i = blockIdx.x * 256 + threadIdx.x;
    if (i < n4) {
        float4 s = S[i], p = P[i];
        s.x = 2.f * s.x - p.x;
        s.y = 2.f * s.y - p.y;
        s.z = 2.f * s.z - p.z;
        s.w = 2.f * s.w - p.w;
        S[i] = s;
        P[i] = make_float4(0.f, 0.f, 0.f, 0.f);
    }
}

// ---------------- y[n,g,b] += sum_d T[n,d,b] * W[d,g] ----------------
template <int RD, int SD, int G>
__global__ void k_accum(const float* __restrict__ Tk, const float* __restrict__ W,
                        float* __restrict__ y, int total) {
    int idx = blockIdx.x * 256 + threadIdx.x;
    if (idx < total) {
        int n = idx / (G * 4);
        int g = (idx >> 2) & (G - 1);
        int b = idx & 3;
        const float* tp = Tk + n * SD + b;
        float acc = 0.f;
#pragma unroll
        for (int d = 0; d < RD; ++d) acc = fmaf(tp[d * 4], W[d * G + g], acc);
        y[idx] += acc;
    }
}

// ---------------- b_map GEMM: C[m,j] = sum_n A[m,n] * relu(y1[n,j]+b1[j>>2]) ----------------
#define GBM 64
#define GBN 64
#define GBK 32
__global__ __launch_bounds__(256) void k_gemm_bmap(const float* __restrict__ A,
                                                   const float* __restrict__ y1,
                                                   const float* __restrict__ b1v,
                                                   float* __restrict__ C) {
    __shared__ float As[GBK][GBM + 1];  // [kk][m], padded
    __shared__ float Bs[GBK][GBN];      // [kk][j]
    int m0 = blockIdx.x * GBM, j0 = blockIdx.y * GBN;
    int t = threadIdx.x;
    int tm = t >> 4, tn = t & 15;
    float acc[4][4] = {};
    for (int k0 = 0; k0 < NN1; k0 += GBK) {
#pragma unroll
        for (int i = 0; i < 8; ++i) {          // A tile: 64m x 32k
            int l = i * 256 + t;
            int m = l >> 5, kk = l & 31;
            As[kk][m] = A[(m0 + m) * NN1 + k0 + kk];
        }
#pragma unroll
        for (int i = 0; i < 8; ++i) {          // B tile: 32k x 64j, fused bias+relu
            int l = i * 256 + t;
            int kk = l >> 6, j = l & 63;
            float v = y1[(k0 + kk) * 256 + j0 + j] + b1v[(j0 + j) >> 2];
            Bs[kk][j] = fmaxf(v, 0.f);
        }
        __syncthreads();
#pragma unroll
        for (int kk = 0; kk < GBK; ++kk) {
            float a[4], b[4];
#pragma unroll
            for (int i = 0; i < 4; ++i) a[i] = As[kk][tm * 4 + i];
#pragma unroll
            for (int j = 0; j < 4; ++j) b[j] = Bs[kk][tn * 4 + j];
#pragma unroll
            for (int i = 0; i < 4; ++i)
#pragma unroll
                for (int j = 0; j < 4; ++j) acc[i][j] = fmaf(a[i], b[j], acc[i][j]);
        }
        __syncthreads();
    }
#pragma unroll
    for (int i = 0; i < 4; ++i)
#pragma unroll
        for (int j = 0; j < 4; ++j)
            C[(m0 + tm * 4 + i) * 256 + j0 + tn * 4 + j] = acc[i][j];
}

// ---------------- fc: logits[q,c] = sum_i (y2flat[q*131072+i]+b2[g]) * fcw[c,i] ----------------
__global__ __launch_bounds__(256) void k_fc(const float* __restrict__ y2, const float* __restrict__ b2,
                                            const float* __restrict__ fcw, const float* __restrict__ fcb,
                                            float* __restrict__ logits) {
    int q = blockIdx.x / NCLS, c = blockIdx.x % NCLS;
    const float* yp = y2 + q * 131072;
    const float* wp = fcw + c * 131072;
    float acc = 0.f;
    for (int i = threadIdx.x; i < 131072; i += 256) {
        int g = (i >> 2) & 31;
        acc = fmaf(yp[i] + b2[g], wp[i], acc);
    }
    __shared__ float red[4];
#pragma unroll
    for (int o = 32; o; o >>= 1) acc += __shfl_down(acc, o, 64);
    if ((threadIdx.x & 63) == 0) red[threadIdx.x >> 6] = acc;
    __syncthreads();
    if (threadIdx.x == 0)
        logits[q * NCLS + c] = red[0] + red[1] + red[2] + red[3] + fcb[c];
}

__global__ void k_lsm(const float* __restrict__ logits, float* __restrict__ out) {
    int q = threadIdx.x;
    if (q < NB) {
        float m = -1e30f;
        for (int c = 0; c < NCLS; ++c) m = fmaxf(m, logits[q * NCLS + c]);
        float s = 0.f;
        for (int c = 0; c < NCLS; ++c) s += expf(logits[q * NCLS + c] - m);
        float lse = m + logf(s);
        for (int c = 0; c < NCLS; ++c) out[q * NCLS + c] = logits[q * NCLS + c] - lse;
    }
}

extern "C" void kernel_launch(void* const* d_in, const int* in_sizes, int n_in,
                              void* d_out, int out_size, void* d_ws, size_t ws_size,
                              hipStream_t stream) {
    const float* x    = (const float*)d_in[0];
    const int*   ei1  = (const int*)d_in[1];
    const float* ew1  = (const float*)d_in[2];
    const int*   ei2  = (const int*)d_in[3];
    const float* ew2  = (const float*)d_in[4];
    const float* bmap = (const float*)d_in[5];
    const float* W1   = (const float*)d_in[6];
    const float* b1   = (const float*)d_in[7];
    const float* W2   = (const float*)d_in[8];
    const float* b2   = (const float*)d_in[9];
    const float* fcw  = (const float*)d_in[10];
    const float* fcb  = (const float*)d_in[11];
    float* out = (float*)d_out;

    char* w = (char*)d_ws;
    size_t o = 0;
    auto alloc = [&](size_t bytes) {
        char* p = w + o;
        o += (bytes + 255) & ~(size_t)255;
        return p;
    };
    float* norm1 = (float*)alloc(EE1 * 4);
    float* norm2 = (float*)alloc(EE2 * 4);
    float* deg1  = (float*)alloc(NN1 * 4);
    float* deg2  = (float*)alloc(NN2 * 4);
    float* bA1 = (float*)alloc(NN1 * 64 * 4);
    float* bB1 = (float*)alloc(NN1 * 64 * 4);
    float* bC1 = (float*)alloc(NN1 * 64 * 4);
    float* y1  = (float*)alloc(NN1 * 256 * 4);
    float* bA2 = (float*)alloc((size_t)NN2 * 256 * 4);
    float* bB2 = (float*)alloc((size_t)NN2 * 256 * 4);
    float* bC2 = (float*)alloc((size_t)NN2 * 256 * 4);
    float* y2  = (float*)alloc(NN2 * 128 * 4);
    float* logits = (float*)alloc(256);

    // norms
    hipMemsetAsync(deg1, 0, NN1 * 4, stream);
    hipMemsetAsync(deg2, 0, NN2 * 4, stream);
    k_deg<<<EE1 / 256, 256, 0, stream>>>(ei1, ew1, deg1, EE1);
    k_deg<<<EE2 / 256, 256, 0, stream>>>(ei2, ew2, deg2, EE2);
    k_norm<<<EE1 / 256, 256, 0, stream>>>(ei1, ew1, deg1, norm1, EE1);
    k_norm<<<EE2 / 256, 256, 0, stream>>>(ei2, ew2, deg2, norm2, EE2);

    // ---- conv1 (D=60 pad 64, G=64) ----
    k_build_h0<<<(NN1 * 60 + 255) / 256, 256, 0, stream>>>(x, bA1);
    hipMemsetAsync(y1, 0, NN1 * 256 * 4, stream);
    k_accum<15, 64, 64><<<NN1 * 256 / 256, 256, 0, stream>>>(bA1, W1, y1, NN1 * 256);
    hipMemsetAsync(bB1, 0, NN1 * 64 * 4, stream);
    k_prop<60, 64, 6><<<EE1 * 64 / 256, 256, 0, stream>>>(bA1, bB1, ei1, norm1, EE1);
    k_accum<15, 64, 64><<<NN1 * 256 / 256, 256, 0, stream>>>(bB1, W1 + TT * GG1, y1, NN1 * 256);
    hipMemsetAsync(bC1, 0, NN1 * 64 * 4, stream);
    {
        float *prev = bA1, *cur = bB1, *nxt = bC1;
        for (int k = 2; k < KCH; ++k) {
            k_prop<60, 64, 6><<<EE1 * 64 / 256, 256, 0, stream>>>(cur, nxt, ei1, norm1, EE1);
            k_combine<<<NN1 * 16 / 256, 256, 0, stream>>>((float4*)nxt, (float4*)prev, NN1 * 16);
            k_accum<15, 64, 64><<<NN1 * 256 / 256, 256, 0, stream>>>(nxt, W1 + k * TT * GG1, y1, NN1 * 256);
            float* tmp = prev; prev = cur; cur = nxt; nxt = tmp;  // nxt zeroed by k_combine
        }
    }

    // ---- b_map GEMM: bA2 = bmap @ relu(y1 + b1) ----
    dim3 gg(NN2 / GBM, 256 / GBN);
    k_gemm_bmap<<<gg, 256, 0, stream>>>(bmap, y1, b1, bA2);

    // ---- conv2 (D=256, G=32) ----
    hipMemsetAsync(y2, 0, NN2 * 128 * 4, stream);
    k_accum<64, 256, 32><<<NN2 * 128 / 256, 256, 0, stream>>>(bA2, W2, y2, NN2 * 128);
    hipMemsetAsync(bB2, 0, (size_t)NN2 * 256 * 4, stream);
    k_prop<256, 256, 8><<<EE2 * 256 / 256, 256, 0, stream>>>(bA2, bB2, ei2, norm2, EE2);
    k_accum<64, 256, 32><<<NN2 * 128 / 256, 256, 0, stream>>>(bB2, W2 + GG1 * GG2, y2, NN2 * 128);
    hipMemsetAsync(bC2, 0, (size_t)NN2 * 256 * 4, stream);
    {
        float *prev = bA2, *cur = bB2, *nxt = bC2;
        for (int k = 2; k < KCH; ++k) {
            k_prop<256, 256, 8><<<EE2 * 256 / 256, 256, 0, stream>>>(cur, nxt, ei2, norm2, EE2);
            k_combine<<<NN2 * 64 / 256, 256, 0, stream>>>((float4*)nxt, (float4*)prev, NN2 * 64);
            k_accum<64, 256, 32><<<NN2 * 128 / 256, 256, 0, stream>>>(nxt, W2 + k * GG1 * GG2, y2, NN2 * 128);
            float* tmp = prev; prev = cur; cur = nxt; nxt = tmp;
        }
    }

    // ---- fc + log_softmax ----
    k_fc<<<NB * NCLS, 256, 0, stream>>>(y2, b2, fcw, fcb, logits);
    k_lsm<<<1, 64, 0, stream>>>(logits, out);
}

// Round 2
// 1828.912 us; speedup vs baseline: 1.1749x; 1.1749x over previous
//
#include <hip/hip_runtime.h>

#define NB   4
#define NN1  8192
#define TT   15
#define NN2  4096
#define KCH  12
#define GG1  64
#define GG2  32
#define NCLS 6
#define EE1  131072
#define EE2  65536

typedef __attribute__((ext_vector_type(8))) short bf16x8;
typedef __attribute__((ext_vector_type(4))) float f32x4;

__device__ inline short f2bf(float f) {
    unsigned u = __builtin_bit_cast(unsigned, f);
    u += 0x7FFFu + ((u >> 16) & 1u);   // RNE
    return (short)(u >> 16);
}

// ---------------- degree / norm ----------------
__global__ void k_deg(const int* __restrict__ ei, const float* __restrict__ w,
                      float* __restrict__ deg, int E) {
    int e = blockIdx.x * 256 + threadIdx.x;
    if (e < E) atomicAdd(&deg[ei[E + e]], w[e]);   // segment_sum over dst
}

__global__ void k_norm(const int* __restrict__ ei, const float* __restrict__ w,
                       const float* __restrict__ deg, float* __restrict__ nrm, int E) {
    int e = blockIdx.x * 256 + threadIdx.x;
    if (e < E) {
        float ds = deg[ei[e]], dd = deg[ei[E + e]];
        float is = ds > 0.f ? 1.f / sqrtf(ds) : 0.f;
        float id = dd > 0.f ? 1.f / sqrtf(dd) : 0.f;
        nrm[e] = -w[e] * is * id;                  // L_hat = -D^-1/2 A D^-1/2
    }
}

// ---------------- build h0: x (B,N1,T) -> (N1, T*4[pad 64]) ----------------
__global__ void k_build_h0(const float* __restrict__ x, float* __restrict__ h0) {
    int idx = blockIdx.x * 256 + threadIdx.x;
    if (idx < NN1 * 60) {
        int n = idx / 60, r = idx - n * 60;
        int t = r >> 2, b = r & 3;
        h0[n * 64 + r] = x[(b * NN1 + n) * TT + t];
    }
}

// ---------------- propagation: S[dst] += norm * h[src] ----------------
template <int D, int SD, int LOG2DP>
__global__ void k_prop(const float* __restrict__ h, float* __restrict__ S,
                       const int* __restrict__ ei, const float* __restrict__ nrm, int E) {
    int tid = blockIdx.x * 256 + threadIdx.x;
    int e = tid >> LOG2DP, j = tid & ((1 << LOG2DP) - 1);
    if (e < E && j < D) {
        int s = ei[e], d = ei[E + e];
        atomicAdd(&S[d * SD + j], nrm[e] * h[s * SD + j]);
    }
}

// ---------------- T_next = 2*S - T_prev; T_prev <- 0 (becomes next S buffer) ----------------
__global__ void k_combine(float4* __restrict__ S, float4* __restrict__ P, int n4) {
    int i = blockIdx.x * 256 + threadIdx.x;
    if (i < n4) {
        float4 s = S[i], p = P[i];
        s.x = 2.f * s.x - p.x;
        s.y = 2.f * s.y - p.y;
        s.z = 2.f * s.z - p.z;
        s.w = 2.f * s.w - p.w;
        S[i] = s;
        P[i] = make_float4(0.f, 0.f, 0.f, 0.f);
    }
}

// ---------------- y[n,g,b] += sum_d T[n,d,b] * W[d,g] ----------------
template <int RD, int SD, int G>
__global__ void k_accum(const float* __restrict__ Tk, const float* __restrict__ W,
                        float* __restrict__ y, int total) {
    int idx = blockIdx.x * 256 + threadIdx.x;
    if (idx < total) {
        int n = idx / (G * 4);
        int g = (idx >> 2) & (G - 1);
        int b = idx & 3;
        const float* tp = Tk + n * SD + b;
        float acc = 0.f;
#pragma unroll
        for (int d = 0; d < RD; ++d) acc = fmaf(tp[d * 4], W[d * G + g], acc);
        y[idx] += acc;
    }
}

// ---------------- b_map GEMM via bf16 MFMA ----------------
// C[m,j] = sum_k A[m,k] * relu(y1[k,j]+b1[j>>2]);  M=4096,K=8192,N=256
// tiles: BM=BN=BK=64, 256 thr = 4 waves (2x2), each wave 32x32 out.
#define PADK 72   // bf16 elems per LDS row (row stride 144B: 16B-aligned, 2-way-max read conflicts)
__global__ __launch_bounds__(256) void k_gemm_mfma(const float* __restrict__ A,
                                                   const float* __restrict__ y1,
                                                   const float* __restrict__ b1v,
                                                   float* __restrict__ C) {
    __shared__ short As[64][PADK];   // [m][k] bf16
    __shared__ short Bs[64][PADK];   // [j][k] bf16 (transposed on store)
    int m0 = blockIdx.x * 64, j0 = blockIdx.y * 64;
    int t = threadIdx.x;
    int lane = t & 63, wid = t >> 6;
    int wm = (wid >> 1) * 32, wn = (wid & 1) * 32;
    int lc = lane & 15, kg = lane >> 4;          // frag col/row index, k-group

    // stage indices
    int am = t >> 2;                              // A row handled by this thread
    int akq = (t & 3) * 4;                        // A k base (then +16 per q)
    int bjq = t & 15;                             // B j-quad
    int bk4 = (t >> 4) * 4;                       // B k base (4 rows)
    float bias = b1v[(j0 >> 2) + bjq];

    f32x4 acc[2][2] = {};

    for (int k0 = 0; k0 < NN1; k0 += 64) {
        // ---- stage A tile 64x64 fp32 -> bf16 LDS ----
        const float* ap = A + (size_t)(m0 + am) * NN1 + k0 + akq;
#pragma unroll
        for (int q = 0; q < 4; ++q) {
            float4 v = *(const float4*)(ap + 16 * q);
            short4 s;
            s.x = f2bf(v.x); s.y = f2bf(v.y); s.z = f2bf(v.z); s.w = f2bf(v.w);
            *(short4*)&As[am][akq + 16 * q] = s;
        }
        // ---- stage B tile 64k x 64j fp32 -> bf16 LDS transposed [j][k] ----
        float4 bv[4];
#pragma unroll
        for (int r = 0; r < 4; ++r) {
            const float* bp = y1 + (size_t)(k0 + bk4 + r) * 256 + j0 + bjq * 4;
            float4 v = *(const float4*)bp;
            v.x = fmaxf(v.x + bias, 0.f);
            v.y = fmaxf(v.y + bias, 0.f);
            v.z = fmaxf(v.z + bias, 0.f);
            v.w = fmaxf(v.w + bias, 0.f);
            bv[r] = v;
        }
#pragma unroll
        for (int jj = 0; jj < 4; ++jj) {
            short4 s;
            s.x = f2bf(jj == 0 ? bv[0].x : jj == 1 ? bv[0].y : jj == 2 ? bv[0].z : bv[0].w);
            s.y = f2bf(jj == 0 ? bv[1].x : jj == 1 ? bv[1].y : jj == 2 ? bv[1].z : bv[1].w);
            s.z = f2bf(jj == 0 ? bv[2].x : jj == 1 ? bv[2].y : jj == 2 ? bv[2].z : bv[2].w);
            s.w = f2bf(jj == 0 ? bv[3].x : jj == 1 ? bv[3].y : jj == 2 ? bv[3].z : bv[3].w);
            *(short4*)&Bs[bjq * 4 + jj][bk4] = s;
        }
        __syncthreads();
        // ---- MFMA: 2 k-steps of 32, 2x2 16x16 frags per wave ----
#pragma unroll
        for (int ks = 0; ks < 2; ++ks) {
            int kk = ks * 32 + kg * 8;
            bf16x8 a[2], b[2];
#pragma unroll
            for (int mi = 0; mi < 2; ++mi) a[mi] = *(bf16x8*)&As[wm + mi * 16 + lc][kk];
#pragma unroll
            for (int ni = 0; ni < 2; ++ni) b[ni] = *(bf16x8*)&Bs[wn + ni * 16 + lc][kk];
#pragma unroll
            for (int mi = 0; mi < 2; ++mi)
#pragma unroll
                for (int ni = 0; ni < 2; ++ni)
                    acc[mi][ni] = __builtin_amdgcn_mfma_f32_16x16x32_bf16(a[mi], b[ni], acc[mi][ni], 0, 0, 0);
        }
        __syncthreads();
    }
    // ---- epilogue: C row = wm+mi*16+kg*4+r, col = wn+ni*16+lc ----
#pragma unroll
    for (int mi = 0; mi < 2; ++mi)
#pragma unroll
        for (int ni = 0; ni < 2; ++ni)
#pragma unroll
            for (int r = 0; r < 4; ++r)
                C[(size_t)(m0 + wm + mi * 16 + kg * 4 + r) * 256 + j0 + wn + ni * 16 + lc] =
                    acc[mi][ni][r];
}

// ---------------- fc: logits[q,c] = sum_i (y2flat[q*131072+i]+b2[g]) * fcw[c,i] ----------------
__global__ __launch_bounds__(256) void k_fc(const float* __restrict__ y2, const float* __restrict__ b2,
                                            const float* __restrict__ fcw, const float* __restrict__ fcb,
                                            float* __restrict__ logits) {
    int q = blockIdx.x / NCLS, c = blockIdx.x % NCLS;
    const float* yp = y2 + q * 131072;
    const float* wp = fcw + c * 131072;
    float acc = 0.f;
    for (int i = threadIdx.x; i < 131072; i += 256) {
        int g = (i >> 2) & 31;
        acc = fmaf(yp[i] + b2[g], wp[i], acc);
    }
    __shared__ float red[4];
#pragma unroll
    for (int o = 32; o; o >>= 1) acc += __shfl_down(acc, o, 64);
    if ((threadIdx.x & 63) == 0) red[threadIdx.x >> 6] = acc;
    __syncthreads();
    if (threadIdx.x == 0)
        logits[q * NCLS + c] = red[0] + red[1] + red[2] + red[3] + fcb[c];
}

__global__ void k_lsm(const float* __restrict__ logits, float* __restrict__ out) {
    int q = threadIdx.x;
    if (q < NB) {
        float m = -1e30f;
        for (int c = 0; c < NCLS; ++c) m = fmaxf(m, logits[q * NCLS + c]);
        float s = 0.f;
        for (int c = 0; c < NCLS; ++c) s += expf(logits[q * NCLS + c] - m);
        float lse = m + logf(s);
        for (int c = 0; c < NCLS; ++c) out[q * NCLS + c] = logits[q * NCLS + c] - lse;
    }
}

extern "C" void kernel_launch(void* const* d_in, const int* in_sizes, int n_in,
                              void* d_out, int out_size, void* d_ws, size_t ws_size,
                              hipStream_t stream) {
    const float* x    = (const float*)d_in[0];
    const int*   ei1  = (const int*)d_in[1];
    const float* ew1  = (const float*)d_in[2];
    const int*   ei2  = (const int*)d_in[3];
    const float* ew2  = (const float*)d_in[4];
    const float* bmap = (const float*)d_in[5];
    const float* W1   = (const float*)d_in[6];
    const float* b1   = (const float*)d_in[7];
    const float* W2   = (const float*)d_in[8];
    const float* b2   = (const float*)d_in[9];
    const float* fcw  = (const float*)d_in[10];
    const float* fcb  = (const float*)d_in[11];
    float* out = (float*)d_out;

    char* w = (char*)d_ws;
    size_t o = 0;
    auto alloc = [&](size_t bytes) {
        char* p = w + o;
        o += (bytes + 255) & ~(size_t)255;
        return p;
    };
    float* norm1 = (float*)alloc(EE1 * 4);
    float* norm2 = (float*)alloc(EE2 * 4);
    float* deg1  = (float*)alloc(NN1 * 4);
    float* deg2  = (float*)alloc(NN2 * 4);
    float* bA1 = (float*)alloc(NN1 * 64 * 4);
    float* bB1 = (float*)alloc(NN1 * 64 * 4);
    float* bC1 = (float*)alloc(NN1 * 64 * 4);
    float* y1  = (float*)alloc(NN1 * 256 * 4);
    float* bA2 = (float*)alloc((size_t)NN2 * 256 * 4);
    float* bB2 = (float*)alloc((size_t)NN2 * 256 * 4);
    float* bC2 = (float*)alloc((size_t)NN2 * 256 * 4);
    float* y2  = (float*)alloc(NN2 * 128 * 4);
    float* logits = (float*)alloc(256);

    // norms
    hipMemsetAsync(deg1, 0, NN1 * 4, stream);
    hipMemsetAsync(deg2, 0, NN2 * 4, stream);
    k_deg<<<EE1 / 256, 256, 0, stream>>>(ei1, ew1, deg1, EE1);
    k_deg<<<EE2 / 256, 256, 0, stream>>>(ei2, ew2, deg2, EE2);
    k_norm<<<EE1 / 256, 256, 0, stream>>>(ei1, ew1, deg1, norm1, EE1);
    k_norm<<<EE2 / 256, 256, 0, stream>>>(ei2, ew2, deg2, norm2, EE2);

    // ---- conv1 (D=60 pad 64, G=64) ----
    k_build_h0<<<(NN1 * 60 + 255) / 256, 256, 0, stream>>>(x, bA1);
    hipMemsetAsync(y1, 0, NN1 * 256 * 4, stream);
    k_accum<15, 64, 64><<<NN1 * 256 / 256, 256, 0, stream>>>(bA1, W1, y1, NN1 * 256);
    hipMemsetAsync(bB1, 0, NN1 * 64 * 4, stream);
    k_prop<60, 64, 6><<<EE1 * 64 / 256, 256, 0, stream>>>(bA1, bB1, ei1, norm1, EE1);
    k_accum<15, 64, 64><<<NN1 * 256 / 256, 256, 0, stream>>>(bB1, W1 + TT * GG1, y1, NN1 * 256);
    hipMemsetAsync(bC1, 0, NN1 * 64 * 4, stream);
    {
        float *prev = bA1, *cur = bB1, *nxt = bC1;
        for (int k = 2; k < KCH; ++k) {
            k_prop<60, 64, 6><<<EE1 * 64 / 256, 256, 0, stream>>>(cur, nxt, ei1, norm1, EE1);
            k_combine<<<NN1 * 16 / 256, 256, 0, stream>>>((float4*)nxt, (float4*)prev, NN1 * 16);
            k_accum<15, 64, 64><<<NN1 * 256 / 256, 256, 0, stream>>>(nxt, W1 + k * TT * GG1, y1, NN1 * 256);
            float* tmp = prev; prev = cur; cur = nxt; nxt = tmp;  // nxt zeroed by k_combine
        }
    }

    // ---- b_map GEMM (bf16 MFMA): bA2 = bmap @ relu(y1 + b1) ----
    dim3 gg(NN2 / 64, 256 / 64);
    k_gemm_mfma<<<gg, 256, 0, stream>>>(bmap, y1, b1, bA2);

    // ---- conv2 (D=256, G=32) ----
    hipMemsetAsync(y2, 0, NN2 * 128 * 4, stream);
    k_accum<64, 256, 32><<<NN2 * 128 / 256, 256, 0, stream>>>(bA2, W2, y2, NN2 * 128);
    hipMemsetAsync(bB2, 0, (size_t)NN2 * 256 * 4, stream);
    k_prop<256, 256, 8><<<EE2 * 256 / 256, 256, 0, stream>>>(bA2, bB2, ei2, norm2, EE2);
    k_accum<64, 256, 32><<<NN2 * 128 / 256, 256, 0, stream>>>(bB2, W2 + GG1 * GG2, y2, NN2 * 128);
    hipMemsetAsync(bC2, 0, (size_t)NN2 * 256 * 4, stream);
    {
        float *prev = bA2, *cur = bB2, *nxt = bC2;
        for (int k = 2; k < KCH; ++k) {
            k_prop<256, 256, 8><<<EE2 * 256 / 256, 256, 0, stream>>>(cur, nxt, ei2, norm2, EE2);
            k_combine<<<NN2 * 64 / 256, 256, 0, stream>>>((float4*)nxt, (float4*)prev, NN2 * 64);
            k_accum<64, 256, 32><<<NN2 * 128 / 256, 256, 0, stream>>>(nxt, W2 + k * GG1 * GG2, y2, NN2 * 128);
            float* tmp = prev; prev = cur; cur = nxt; nxt = tmp;
        }
    }

    // ---- fc + log_softmax ----
    k_fc<<<NB * NCLS, 256, 0, stream>>>(y2, b2, fcw, fcb, logits);
    k_lsm<<<1, 64, 0, stream>>>(logits, out);
}

// Round 3
// 960.029 us; speedup vs baseline: 2.2382x; 1.9051x over previous
//
#include <hip/hip_runtime.h>

#define NB   4
#define NN1  8192
#define TT   15
#define NN2  4096
#define KCH  12
#define GG1  64
#define GG2  32
#define NCLS 6
#define EE1  131072
#define EE2  65536

typedef __attribute__((ext_vector_type(8))) short bf16x8;
typedef __attribute__((ext_vector_type(4))) float f32x4;

__device__ inline short f2bf(float f) {
    unsigned u = __builtin_bit_cast(unsigned, f);
    u += 0x7FFFu + ((u >> 16) & 1u);   // RNE
    return (short)(u >> 16);
}

// ---------------- degree + histogram ----------------
__global__ void k_deg_hist(const int* __restrict__ ei, const float* __restrict__ w,
                           float* __restrict__ deg, int* __restrict__ cnt, int E) {
    int e = blockIdx.x * 256 + threadIdx.x;
    if (e < E) {
        int d = ei[E + e];
        atomicAdd(&deg[d], w[e]);
        atomicAdd(&cnt[d], 1);
    }
}

// ---------------- exclusive scan (single block) ----------------
template <int N>
__global__ __launch_bounds__(1024) void k_scan(const int* __restrict__ cnt,
                                               int* __restrict__ offs, int* __restrict__ cur) {
    constexpr int PER = N / 1024;
    __shared__ int part[1024];
    int t = threadIdx.x;
    int loc[PER];
    int s = 0;
#pragma unroll
    for (int i = 0; i < PER; ++i) { loc[i] = s; s += cnt[t * PER + i]; }
    part[t] = s;
    __syncthreads();
    for (int off = 1; off < 1024; off <<= 1) {
        int v = (t >= off) ? part[t - off] : 0;
        __syncthreads();
        part[t] += v;
        __syncthreads();
    }
    int pre = t ? part[t - 1] : 0;
#pragma unroll
    for (int i = 0; i < PER; ++i) { int v = pre + loc[i]; offs[t * PER + i] = v; cur[t * PER + i] = v; }
    if (t == 1023) offs[N] = part[1023];
}

// ---------------- CSR fill (norm computed inline) ----------------
__global__ void k_fill(const int* __restrict__ ei, const float* __restrict__ w,
                       const float* __restrict__ deg, int* __restrict__ cur,
                       int* __restrict__ csrc, float* __restrict__ cnrm, int E) {
    int e = blockIdx.x * 256 + threadIdx.x;
    if (e < E) {
        int s = ei[e], d = ei[E + e];
        float ds = deg[s], dd = deg[d];
        float is = ds > 0.f ? 1.f / sqrtf(ds) : 0.f;
        float id = dd > 0.f ? 1.f / sqrtf(dd) : 0.f;
        int p = atomicAdd(&cur[d], 1);
        csrc[p] = s;
        cnrm[p] = -w[e] * is * id;
    }
}

// ---------------- build h0: x (B,N1,T) -> fp32 [N1][64] + bf16 slab0 [N1][768] ----------------
__global__ void k_build_h0(const float* __restrict__ x, float* __restrict__ h0,
                           short* __restrict__ bf0) {
    int idx = blockIdx.x * 256 + threadIdx.x;
    if (idx < NN1 * 60) {
        int n = idx / 60, r = idx - n * 60;
        int t = r >> 2, b = r & 3;
        float v = x[(b * NN1 + n) * TT + t];
        h0[n * 64 + r] = v;
        bf0[n * 768 + r] = f2bf(v);
    }
}

// ---------------- CSR prop: T = (first? S : 2S - prev), S[n,j]=sum_e nrm*h[src,j] ----------------
template <int SD, int BST>
__global__ __launch_bounds__(256) void k_prop(const float* __restrict__ hprev,
                                              const float* __restrict__ hprev2,
                                              float* __restrict__ hout, short* __restrict__ bfs,
                                              const int* __restrict__ offs,
                                              const int* __restrict__ csrc,
                                              const float* __restrict__ cnrm, int first) {
    constexpr int CH = SD / 64;
    int w = (blockIdx.x * 256 + threadIdx.x) >> 6;
    int lane = threadIdx.x & 63;
    int n = w / CH, ch = w % CH;
    int j = ch * 64 + lane;
    int e0 = offs[n], e1 = offs[n + 1];
    float a0 = 0.f, a1 = 0.f;
    int e = e0;
    for (; e + 1 < e1; e += 2) {
        a0 = fmaf(cnrm[e],     hprev[(size_t)csrc[e] * SD + j],     a0);
        a1 = fmaf(cnrm[e + 1], hprev[(size_t)csrc[e + 1] * SD + j], a1);
    }
    if (e < e1) a0 = fmaf(cnrm[e], hprev[(size_t)csrc[e] * SD + j], a0);
    float s = a0 + a1;
    float t = first ? s : 2.f * s - hprev2[(size_t)n * SD + j];
    hout[(size_t)n * SD + j] = t;
    bfs[(size_t)n * BST + j] = f2bf(t);
}

// ---------------- block-diagonal weights, stored TRANSPOSED [N][K] bf16 ----------------
__global__ void k_w1p(const float* __restrict__ W1, short* __restrict__ W1p) {
    int idx = blockIdx.x * 256 + threadIdx.x;   // 256 * 768
    if (idx < 256 * 768) {
        int j = idx / 768, d = idx - j * 768;
        int g = j >> 2, b = j & 3;
        int k = d >> 6, r = d & 63, t = r >> 2, bp = r & 3;
        float v = (b == bp && t < TT) ? W1[k * (TT * GG1) + t * GG1 + g] : 0.f;
        W1p[idx] = f2bf(v);
    }
}
__global__ void k_w2p(const float* __restrict__ W2, short* __restrict__ W2p) {
    int idx = blockIdx.x * 256 + threadIdx.x;   // 128 * 3072
    if (idx < 128 * 3072) {
        int j = idx / 3072, d = idx - j * 3072;
        int g = j >> 2, b = j & 3;
        int k = d >> 8, r = d & 255, G = r >> 2, bp = r & 3;
        float v = (b == bp) ? W2[k * (GG1 * GG2) + G * GG2 + g] : 0.f;
        W2p[idx] = f2bf(v);
    }
}

// ---------------- unified MFMA GEMM: C[m,j] = sum_k A[m,k]*B'[k,j] ----------------
// A: fp32 [M][lda] or bf16 [M][lda].  B: fp32 [K][ldb] (k-major, opt bias+relu)
//    or bf16 [N][ldb] (j-major, prebuilt transposed).
// 64x64 tile, BK=64, 4 waves (2x2), XOR-swizzled LDS (col ^= (row&7)<<3).
template <bool A_BF, bool B_BF, bool BIASRELU, bool BF_OUT>
__global__ __launch_bounds__(256) void k_gemm(const void* __restrict__ Ap, int lda,
                                              const void* __restrict__ Bp, int ldb,
                                              const float* __restrict__ bias,
                                              float* __restrict__ Cf, int ldc,
                                              short* __restrict__ Cbf, int ldcbf, int K) {
    __shared__ short As[64][64];
    __shared__ short Bs[64][64];
    int m0 = blockIdx.x * 64, j0 = blockIdx.y * 64;
    int t = threadIdx.x;
    int lane = t & 63, wid = t >> 6;
    int wm = (wid >> 1) * 32, wn = (wid & 1) * 32;
    int lc = lane & 15, kg = lane >> 4;
    int r4 = t >> 2, c4 = (t & 3) * 16;
    int bjq = t & 15, bk4 = (t >> 4) * 4;
    float bvbias = 0.f;
    if (BIASRELU) bvbias = bias[(j0 >> 2) + bjq];

    f32x4 acc[2][2] = {};

    for (int k0 = 0; k0 < K; k0 += 64) {
        int swa = (r4 & 7) << 3;
        // ---- stage A ----
        if (A_BF) {
            const short* ap = (const short*)Ap + (size_t)(m0 + r4) * lda + k0 + c4;
            bf16x8 v0 = *(const bf16x8*)ap;
            bf16x8 v1 = *(const bf16x8*)(ap + 8);
            *(bf16x8*)&As[r4][c4 ^ swa] = v0;
            *(bf16x8*)&As[r4][(c4 + 8) ^ swa] = v1;
        } else {
            const float* ap = (const float*)Ap + (size_t)(m0 + r4) * lda + k0 + (t & 3) * 4;
#pragma unroll
            for (int q = 0; q < 4; ++q) {
                float4 v = *(const float4*)(ap + 16 * q);
                short4 s;
                s.x = f2bf(v.x); s.y = f2bf(v.y); s.z = f2bf(v.z); s.w = f2bf(v.w);
                *(short4*)&As[r4][((t & 3) * 4 + 16 * q) ^ swa] = s;
            }
        }
        // ---- stage B -> Bs[j][k] ----
        if (B_BF) {
            const short* bp = (const short*)Bp + (size_t)(j0 + r4) * ldb + k0 + c4;
            bf16x8 v0 = *(const bf16x8*)bp;
            bf16x8 v1 = *(const bf16x8*)(bp + 8);
            *(bf16x8*)&Bs[r4][c4 ^ swa] = v0;
            *(bf16x8*)&Bs[r4][(c4 + 8) ^ swa] = v1;
        } else {
            float4 bv[4];
#pragma unroll
            for (int r = 0; r < 4; ++r) {
                const float* bp = (const float*)Bp + (size_t)(k0 + bk4 + r) * ldb + j0 + bjq * 4;
                float4 v = *(const float4*)bp;
                if (BIASRELU) {
                    v.x = fmaxf(v.x + bvbias, 0.f);
                    v.y = fmaxf(v.y + bvbias, 0.f);
                    v.z = fmaxf(v.z + bvbias, 0.f);
                    v.w = fmaxf(v.w + bvbias, 0.f);
                }
                bv[r] = v;
            }
#pragma unroll
            for (int jj = 0; jj < 4; ++jj) {
                int row = bjq * 4 + jj;
                int sw = (row & 7) << 3;
                short4 s;
                s.x = f2bf(jj == 0 ? bv[0].x : jj == 1 ? bv[0].y : jj == 2 ? bv[0].z : bv[0].w);
                s.y = f2bf(jj == 0 ? bv[1].x : jj == 1 ? bv[1].y : jj == 2 ? bv[1].z : bv[1].w);
                s.z = f2bf(jj == 0 ? bv[2].x : jj == 1 ? bv[2].y : jj == 2 ? bv[2].z : bv[2].w);
                s.w = f2bf(jj == 0 ? bv[3].x : jj == 1 ? bv[3].y : jj == 2 ? bv[3].z : bv[3].w);
                *(short4*)&Bs[row][bk4 ^ sw] = s;
            }
        }
        __syncthreads();
#pragma unroll
        for (int ks = 0; ks < 2; ++ks) {
            int kk = ks * 32 + kg * 8;
            bf16x8 a[2], b[2];
#pragma unroll
            for (int mi = 0; mi < 2; ++mi) {
                int row = wm + mi * 16 + lc;
                a[mi] = *(bf16x8*)&As[row][kk ^ ((row & 7) << 3)];
            }
#pragma unroll
            for (int ni = 0; ni < 2; ++ni) {
                int row = wn + ni * 16 + lc;
                b[ni] = *(bf16x8*)&Bs[row][kk ^ ((row & 7) << 3)];
            }
#pragma unroll
            for (int mi = 0; mi < 2; ++mi)
#pragma unroll
                for (int ni = 0; ni < 2; ++ni)
                    acc[mi][ni] = __builtin_amdgcn_mfma_f32_16x16x32_bf16(a[mi], b[ni], acc[mi][ni], 0, 0, 0);
        }
        __syncthreads();
    }
#pragma unroll
    for (int mi = 0; mi < 2; ++mi)
#pragma unroll
        for (int ni = 0; ni < 2; ++ni)
#pragma unroll
            for (int r = 0; r < 4; ++r) {
                int row = m0 + wm + mi * 16 + kg * 4 + r, col = j0 + wn + ni * 16 + lc;
                float v = acc[mi][ni][r];
                Cf[(size_t)row * ldc + col] = v;
                if (BF_OUT) Cbf[(size_t)row * ldcbf + col] = f2bf(v);
            }
}

// ---------------- fc partial: logits[qc] += partial dot ----------------
__global__ __launch_bounds__(256) void k_fc(const float* __restrict__ y2, const float* __restrict__ b2,
                                            const float* __restrict__ fcw, float* __restrict__ logits) {
    int qc = blockIdx.x >> 4, ch = blockIdx.x & 15;
    int q = qc / NCLS, c = qc % NCLS;
    const float* yp = y2 + (size_t)q * 131072 + ch * 8192;
    const float* wp = fcw + (size_t)c * 131072 + ch * 8192;
    int t = threadIdx.x;
    float acc = 0.f;
#pragma unroll
    for (int it = 0; it < 8; ++it) {
        int o = it * 1024 + t * 4;
        float4 yv = *(const float4*)(yp + o);
        float4 wv = *(const float4*)(wp + o);
        float bg = b2[((ch * 8192 + o) >> 2) & 31];
        acc += (yv.x + bg) * wv.x + (yv.y + bg) * wv.y + (yv.z + bg) * wv.z + (yv.w + bg) * wv.w;
    }
#pragma unroll
    for (int o = 32; o; o >>= 1) acc += __shfl_down(acc, o, 64);
    __shared__ float red[4];
    if ((t & 63) == 0) red[t >> 6] = acc;
    __syncthreads();
    if (t == 0) atomicAdd(&logits[qc], red[0] + red[1] + red[2] + red[3]);
}

__global__ void k_lsm(const float* __restrict__ logits, const float* __restrict__ fcb,
                      float* __restrict__ out) {
    int q = threadIdx.x;
    if (q < NB) {
        float v[NCLS];
#pragma unroll
        for (int c = 0; c < NCLS; ++c) v[c] = logits[q * NCLS + c] + fcb[c];
        float m = -1e30f;
#pragma unroll
        for (int c = 0; c < NCLS; ++c) m = fmaxf(m, v[c]);
        float s = 0.f;
#pragma unroll
        for (int c = 0; c < NCLS; ++c) s += expf(v[c] - m);
        float lse = m + logf(s);
#pragma unroll
        for (int c = 0; c < NCLS; ++c) out[q * NCLS + c] = v[c] - lse;
    }
}

extern "C" void kernel_launch(void* const* d_in, const int* in_sizes, int n_in,
                              void* d_out, int out_size, void* d_ws, size_t ws_size,
                              hipStream_t stream) {
    const float* x    = (const float*)d_in[0];
    const int*   ei1  = (const int*)d_in[1];
    const float* ew1  = (const float*)d_in[2];
    const int*   ei2  = (const int*)d_in[3];
    const float* ew2  = (const float*)d_in[4];
    const float* bmap = (const float*)d_in[5];
    const float* W1   = (const float*)d_in[6];
    const float* b1   = (const float*)d_in[7];
    const float* W2   = (const float*)d_in[8];
    const float* b2   = (const float*)d_in[9];
    const float* fcw  = (const float*)d_in[10];
    const float* fcb  = (const float*)d_in[11];
    float* out = (float*)d_out;

    char* w = (char*)d_ws;
    size_t o = 0;
    auto alloc = [&](size_t bytes) {
        char* p = w + o;
        o += (bytes + 255) & ~(size_t)255;
        return p;
    };
    float* deg1  = (float*)alloc(NN1 * 4);
    float* deg2  = (float*)alloc(NN2 * 4);
    int*   cnt1  = (int*)alloc(NN1 * 4);
    int*   cnt2  = (int*)alloc(NN2 * 4);
    int*   offs1 = (int*)alloc((NN1 + 1) * 4);
    int*   offs2 = (int*)alloc((NN2 + 1) * 4);
    int*   cur1  = (int*)alloc(NN1 * 4);
    int*   cur2  = (int*)alloc(NN2 * 4);
    int*   csrc1 = (int*)alloc(EE1 * 4);
    float* cnrm1 = (float*)alloc(EE1 * 4);
    int*   csrc2 = (int*)alloc(EE2 * 4);
    float* cnrm2 = (float*)alloc(EE2 * 4);
    float* R1a = (float*)alloc(NN1 * 64 * 4);
    float* R1b = (float*)alloc(NN1 * 64 * 4);
    float* R1c = (float*)alloc(NN1 * 64 * 4);
    short* T1bf = (short*)alloc((size_t)NN1 * 768 * 2);
    float* y1  = (float*)alloc((size_t)NN1 * 256 * 4);
    float* R2a = (float*)alloc((size_t)NN2 * 256 * 4);
    float* R2b = (float*)alloc((size_t)NN2 * 256 * 4);
    float* R2c = (float*)alloc((size_t)NN2 * 256 * 4);
    short* T2bf = (short*)alloc((size_t)NN2 * 3072 * 2);
    float* y2  = (float*)alloc((size_t)NN2 * 128 * 4);
    short* W1p = (short*)alloc(256 * 768 * 2);
    short* W2p = (short*)alloc(128 * 3072 * 2);
    float* logits = (float*)alloc(256);

    // ---- CSR build ----
    hipMemsetAsync(deg1, 0, NN1 * 4, stream);
    hipMemsetAsync(deg2, 0, NN2 * 4, stream);
    hipMemsetAsync(cnt1, 0, NN1 * 4, stream);
    hipMemsetAsync(cnt2, 0, NN2 * 4, stream);
    hipMemsetAsync(logits, 0, 256, stream);
    k_deg_hist<<<EE1 / 256, 256, 0, stream>>>(ei1, ew1, deg1, cnt1, EE1);
    k_deg_hist<<<EE2 / 256, 256, 0, stream>>>(ei2, ew2, deg2, cnt2, EE2);
    k_scan<NN1><<<1, 1024, 0, stream>>>(cnt1, offs1, cur1);
    k_scan<NN2><<<1, 1024, 0, stream>>>(cnt2, offs2, cur2);
    k_fill<<<EE1 / 256, 256, 0, stream>>>(ei1, ew1, deg1, cur1, csrc1, cnrm1, EE1);
    k_fill<<<EE2 / 256, 256, 0, stream>>>(ei2, ew2, deg2, cur2, csrc2, cnrm2, EE2);

    // ---- weights ----
    k_w1p<<<(256 * 768) / 256, 256, 0, stream>>>(W1, W1p);
    k_w2p<<<(128 * 3072) / 256, 256, 0, stream>>>(W2, W2p);

    // ---- conv1: Cheb recursion, T_k -> bf16 slabs ----
    k_build_h0<<<(NN1 * 60 + 255) / 256, 256, 0, stream>>>(x, R1a, T1bf);
    {
        float *Tm1 = R1a, *Tm2 = nullptr, *fr = R1b, *spare = R1c;
        for (int k = 1; k < KCH; ++k) {
            k_prop<64, 768><<<NN1 / 4, 256, 0, stream>>>(Tm1, k == 1 ? Tm1 : Tm2, fr,
                                                         T1bf + k * 64, offs1, csrc1, cnrm1,
                                                         k == 1 ? 1 : 0);
            float* nf = (k == 1) ? spare : Tm2;
            Tm2 = Tm1; Tm1 = fr; fr = nf;
        }
    }
    // y1 = T1bf @ W1p^T   (M=8192, N=256, K=768)
    {
        dim3 g(NN1 / 64, 256 / 64);
        k_gemm<true, true, false, false><<<g, 256, 0, stream>>>(T1bf, 768, W1p, 768, nullptr,
                                                                y1, 256, nullptr, 0, 768);
    }
    // bA2 = bmap @ relu(y1 + b1)  (M=4096, N=256, K=8192), bf16 copy -> T2bf slab0
    {
        dim3 g(NN2 / 64, 256 / 64);
        k_gemm<false, false, true, true><<<g, 256, 0, stream>>>(bmap, NN1, y1, 256, b1,
                                                                R2a, 256, T2bf, 3072, NN1);
    }
    // ---- conv2 ----
    {
        float *Tm1 = R2a, *Tm2 = nullptr, *fr = R2b, *spare = R2c;
        for (int k = 1; k < KCH; ++k) {
            k_prop<256, 3072><<<NN2, 256, 0, stream>>>(Tm1, k == 1 ? Tm1 : Tm2, fr,
                                                       T2bf + k * 256, offs2, csrc2, cnrm2,
                                                       k == 1 ? 1 : 0);
            float* nf = (k == 1) ? spare : Tm2;
            Tm2 = Tm1; Tm1 = fr; fr = nf;
        }
    }
    // y2 = T2bf @ W2p^T   (M=4096, N=128, K=3072)
    {
        dim3 g(NN2 / 64, 128 / 64);
        k_gemm<true, true, false, false><<<g, 256, 0, stream>>>(T2bf, 3072, W2p, 3072, nullptr,
                                                                y2, 128, nullptr, 0, 3072);
    }

    // ---- fc + log_softmax ----
    k_fc<<<NB * NCLS * 16, 256, 0, stream>>>(y2, b2, fcw, logits);
    k_lsm<<<1, 64, 0, stream>>>(logits, fcb, out);
}

// Round 4
// 616.040 us; speedup vs baseline: 3.4879x; 1.5584x over previous
//
#include <hip/hip_runtime.h>

#define NB   4
#define NN1  8192
#define TT   15
#define NN2  4096
#define KCH  12
#define GG1  64
#define GG2  32
#define NCLS 6
#define EE1  131072
#define EE2  65536

typedef __attribute__((ext_vector_type(8))) short bf16x8;
typedef __attribute__((ext_vector_type(4))) float f32x4;

__device__ inline short f2bf(float f) {
    unsigned u = __builtin_bit_cast(unsigned, f);
    u += 0x7FFFu + ((u >> 16) & 1u);   // RNE
    return (short)(u >> 16);
}

// ---------------- degree + histogram ----------------
__global__ void k_deg_hist(const int* __restrict__ ei, const float* __restrict__ w,
                           float* __restrict__ deg, int* __restrict__ cnt, int E) {
    int e = blockIdx.x * 256 + threadIdx.x;
    if (e < E) {
        int d = ei[E + e];
        atomicAdd(&deg[d], w[e]);
        atomicAdd(&cnt[d], 1);
    }
}

// ---------------- exclusive scan (single block) ----------------
template <int N>
__global__ __launch_bounds__(1024) void k_scan(const int* __restrict__ cnt,
                                               int* __restrict__ offs, int* __restrict__ cur) {
    constexpr int PER = N / 1024;
    __shared__ int part[1024];
    int t = threadIdx.x;
    int loc[PER];
    int s = 0;
#pragma unroll
    for (int i = 0; i < PER; ++i) { loc[i] = s; s += cnt[t * PER + i]; }
    part[t] = s;
    __syncthreads();
    for (int off = 1; off < 1024; off <<= 1) {
        int v = (t >= off) ? part[t - off] : 0;
        __syncthreads();
        part[t] += v;
        __syncthreads();
    }
    int pre = t ? part[t - 1] : 0;
#pragma unroll
    for (int i = 0; i < PER; ++i) { int v = pre + loc[i]; offs[t * PER + i] = v; cur[t * PER + i] = v; }
    if (t == 1023) offs[N] = part[1023];
}

// ---------------- CSR fill (norm computed inline) ----------------
__global__ void k_fill(const int* __restrict__ ei, const float* __restrict__ w,
                       const float* __restrict__ deg, int* __restrict__ cur,
                       int* __restrict__ csrc, float* __restrict__ cnrm, int E) {
    int e = blockIdx.x * 256 + threadIdx.x;
    if (e < E) {
        int s = ei[e], d = ei[E + e];
        float ds = deg[s], dd = deg[d];
        float is = ds > 0.f ? 1.f / sqrtf(ds) : 0.f;
        float id = dd > 0.f ? 1.f / sqrtf(dd) : 0.f;
        int p = atomicAdd(&cur[d], 1);
        csrc[p] = s;
        cnrm[p] = -w[e] * is * id;
    }
}

// ---------------- build h0 (pads zeroed) ----------------
__global__ void k_build_h0(const float* __restrict__ x, float* __restrict__ h0,
                           short* __restrict__ bf0) {
    int idx = blockIdx.x * 256 + threadIdx.x;
    if (idx < NN1 * 64) {
        int n = idx >> 6, r = idx & 63;
        float v = 0.f;
        if (r < 60) {
            int t = r >> 2, b = r & 3;
            v = x[(b * NN1 + n) * TT + t];
        }
        h0[idx] = v;
        bf0[(size_t)n * 768 + r] = f2bf(v);
    }
}

// ---------------- conv1 prop: 1 wave/node, 4 edges in flight, float4 feats ----------------
__global__ __launch_bounds__(64) void k_prop1(const float* __restrict__ hprev,
                                              const float* __restrict__ hprev2,
                                              float* __restrict__ hout, short* __restrict__ bfs,
                                              const int* __restrict__ offs,
                                              const int* __restrict__ csrc,
                                              const float* __restrict__ cnrm, int first) {
    int n = blockIdx.x;
    int lane = threadIdx.x;
    int es = lane >> 4, f4 = lane & 15;
    int e0 = offs[n], e1 = offs[n + 1];
    f32x4 acc = {0.f, 0.f, 0.f, 0.f};
    for (int e = e0 + es; e < e1; e += 4) {
        int s = csrc[e];
        float wv = cnrm[e];
        const float4 v = *(const float4*)(hprev + (size_t)s * 64 + f4 * 4);
        acc[0] = fmaf(wv, v.x, acc[0]);
        acc[1] = fmaf(wv, v.y, acc[1]);
        acc[2] = fmaf(wv, v.z, acc[2]);
        acc[3] = fmaf(wv, v.w, acc[3]);
    }
#pragma unroll
    for (int i = 0; i < 4; ++i) {
        acc[i] += __shfl_xor(acc[i], 16, 64);
        acc[i] += __shfl_xor(acc[i], 32, 64);
    }
    if (es == 0) {
        float4 t;
        if (first) {
            t = make_float4(acc[0], acc[1], acc[2], acc[3]);
        } else {
            float4 p = *(const float4*)(hprev2 + (size_t)n * 64 + f4 * 4);
            t = make_float4(2.f * acc[0] - p.x, 2.f * acc[1] - p.y,
                            2.f * acc[2] - p.z, 2.f * acc[3] - p.w);
        }
        *(float4*)(hout + (size_t)n * 64 + f4 * 4) = t;
        short4 s4;
        s4.x = f2bf(t.x); s4.y = f2bf(t.y); s4.z = f2bf(t.z); s4.w = f2bf(t.w);
        *(short4*)(bfs + (size_t)n * 768 + f4 * 4) = s4;
    }
}

// ---------------- conv2 prop: 1 block(4 waves)/node, wave=edge slot, float4 feats ----------------
__global__ __launch_bounds__(256) void k_prop2(const float* __restrict__ hprev,
                                               const float* __restrict__ hprev2,
                                               float* __restrict__ hout, short* __restrict__ bfs,
                                               const int* __restrict__ offs,
                                               const int* __restrict__ csrc,
                                               const float* __restrict__ cnrm, int first) {
    __shared__ f32x4 red[3][64];
    int n = blockIdx.x;
    int t = threadIdx.x;
    int w = t >> 6, lane = t & 63;
    int e0 = offs[n], e1 = offs[n + 1];
    f32x4 acc = {0.f, 0.f, 0.f, 0.f};
    for (int e = e0 + w; e < e1; e += 4) {
        int s = csrc[e];
        float wv = cnrm[e];
        const float4 v = *(const float4*)(hprev + (size_t)s * 256 + lane * 4);
        acc[0] = fmaf(wv, v.x, acc[0]);
        acc[1] = fmaf(wv, v.y, acc[1]);
        acc[2] = fmaf(wv, v.z, acc[2]);
        acc[3] = fmaf(wv, v.w, acc[3]);
    }
    if (w) red[w - 1][lane] = acc;
    __syncthreads();
    if (w == 0) {
        f32x4 s = acc + red[0][lane] + red[1][lane] + red[2][lane];
        float4 tt;
        if (first) {
            tt = make_float4(s[0], s[1], s[2], s[3]);
        } else {
            float4 p = *(const float4*)(hprev2 + (size_t)n * 256 + lane * 4);
            tt = make_float4(2.f * s[0] - p.x, 2.f * s[1] - p.y,
                             2.f * s[2] - p.z, 2.f * s[3] - p.w);
        }
        *(float4*)(hout + (size_t)n * 256 + lane * 4) = tt;
        short4 s4;
        s4.x = f2bf(tt.x); s4.y = f2bf(tt.y); s4.z = f2bf(tt.z); s4.w = f2bf(tt.w);
        *(short4*)(bfs + (size_t)n * 3072 + lane * 4) = s4;
    }
}

// ---------------- block-diagonal weights, stored TRANSPOSED [N][K] bf16 ----------------
__global__ void k_w1p(const float* __restrict__ W1, short* __restrict__ W1p) {
    int idx = blockIdx.x * 256 + threadIdx.x;   // 256 * 768
    if (idx < 256 * 768) {
        int j = idx / 768, d = idx - j * 768;
        int g = j >> 2, b = j & 3;
        int k = d >> 6, r = d & 63, t = r >> 2, bp = r & 3;
        float v = (b == bp && t < TT) ? W1[k * (TT * GG1) + t * GG1 + g] : 0.f;
        W1p[idx] = f2bf(v);
    }
}
__global__ void k_w2p(const float* __restrict__ W2, short* __restrict__ W2p) {
    int idx = blockIdx.x * 256 + threadIdx.x;   // 128 * 3072
    if (idx < 128 * 3072) {
        int j = idx / 3072, d = idx - j * 3072;
        int g = j >> 2, b = j & 3;
        int k = d >> 8, r = d & 255, G = r >> 2, bp = r & 3;
        float v = (b == bp) ? W2[k * (GG1 * GG2) + G * GG2 + g] : 0.f;
        W2p[idx] = f2bf(v);
    }
}

// ---------------- unified MFMA GEMM with split-K ----------------
// C_part[z][m,j] = sum_{k in chunk z} A[m,k]*B'[k,j]
template <bool A_BF, bool B_BF, bool BIASRELU>
__global__ __launch_bounds__(256) void k_gemm(const void* __restrict__ Ap, int lda,
                                              const void* __restrict__ Bp, int ldb,
                                              const float* __restrict__ bias,
                                              float* __restrict__ Cf, int ldc,
                                              int Kc, size_t pstride) {
    __shared__ short As[64][64];
    __shared__ short Bs[64][64];
    int m0 = blockIdx.x * 64, j0 = blockIdx.y * 64;
    int z = blockIdx.z;
    int kbeg = z * Kc, kend = kbeg + Kc;
    float* C = Cf + (size_t)z * pstride;
    int t = threadIdx.x;
    int lane = t & 63, wid = t >> 6;
    int wm = (wid >> 1) * 32, wn = (wid & 1) * 32;
    int lc = lane & 15, kg = lane >> 4;
    int r4 = t >> 2, c4 = (t & 3) * 16;
    int bjq = t & 15, bk4 = (t >> 4) * 4;
    float bvbias = 0.f;
    if (BIASRELU) bvbias = bias[(j0 >> 2) + bjq];

    f32x4 acc[2][2] = {};

    for (int k0 = kbeg; k0 < kend; k0 += 64) {
        int swa = (r4 & 7) << 3;
        // ---- stage A ----
        if (A_BF) {
            const short* ap = (const short*)Ap + (size_t)(m0 + r4) * lda + k0 + c4;
            bf16x8 v0 = *(const bf16x8*)ap;
            bf16x8 v1 = *(const bf16x8*)(ap + 8);
            *(bf16x8*)&As[r4][c4 ^ swa] = v0;
            *(bf16x8*)&As[r4][(c4 + 8) ^ swa] = v1;
        } else {
            const float* ap = (const float*)Ap + (size_t)(m0 + r4) * lda + k0 + (t & 3) * 4;
#pragma unroll
            for (int q = 0; q < 4; ++q) {
                float4 v = *(const float4*)(ap + 16 * q);
                short4 s;
                s.x = f2bf(v.x); s.y = f2bf(v.y); s.z = f2bf(v.z); s.w = f2bf(v.w);
                *(short4*)&As[r4][((t & 3) * 4 + 16 * q) ^ swa] = s;
            }
        }
        // ---- stage B -> Bs[j][k] ----
        if (B_BF) {
            const short* bp = (const short*)Bp + (size_t)(j0 + r4) * ldb + k0 + c4;
            bf16x8 v0 = *(const bf16x8*)bp;
            bf16x8 v1 = *(const bf16x8*)(bp + 8);
            *(bf16x8*)&Bs[r4][c4 ^ swa] = v0;
            *(bf16x8*)&Bs[r4][(c4 + 8) ^ swa] = v1;
        } else {
            float4 bv[4];
#pragma unroll
            for (int r = 0; r < 4; ++r) {
                const float* bp = (const float*)Bp + (size_t)(k0 + bk4 + r) * ldb + j0 + bjq * 4;
                float4 v = *(const float4*)bp;
                if (BIASRELU) {
                    v.x = fmaxf(v.x + bvbias, 0.f);
                    v.y = fmaxf(v.y + bvbias, 0.f);
                    v.z = fmaxf(v.z + bvbias, 0.f);
                    v.w = fmaxf(v.w + bvbias, 0.f);
                }
                bv[r] = v;
            }
#pragma unroll
            for (int jj = 0; jj < 4; ++jj) {
                int row = bjq * 4 + jj;
                int sw = (row & 7) << 3;
                short4 s;
                s.x = f2bf(jj == 0 ? bv[0].x : jj == 1 ? bv[0].y : jj == 2 ? bv[0].z : bv[0].w);
                s.y = f2bf(jj == 0 ? bv[1].x : jj == 1 ? bv[1].y : jj == 2 ? bv[1].z : bv[1].w);
                s.z = f2bf(jj == 0 ? bv[2].x : jj == 1 ? bv[2].y : jj == 2 ? bv[2].z : bv[2].w);
                s.w = f2bf(jj == 0 ? bv[3].x : jj == 1 ? bv[3].y : jj == 2 ? bv[3].z : bv[3].w);
                *(short4*)&Bs[row][bk4 ^ sw] = s;
            }
        }
        __syncthreads();
#pragma unroll
        for (int ks = 0; ks < 2; ++ks) {
            int kk = ks * 32 + kg * 8;
            bf16x8 a[2], b[2];
#pragma unroll
            for (int mi = 0; mi < 2; ++mi) {
                int row = wm + mi * 16 + lc;
                a[mi] = *(bf16x8*)&As[row][kk ^ ((row & 7) << 3)];
            }
#pragma unroll
            for (int ni = 0; ni < 2; ++ni) {
                int row = wn + ni * 16 + lc;
                b[ni] = *(bf16x8*)&Bs[row][kk ^ ((row & 7) << 3)];
            }
#pragma unroll
            for (int mi = 0; mi < 2; ++mi)
#pragma unroll
                for (int ni = 0; ni < 2; ++ni)
                    acc[mi][ni] = __builtin_amdgcn_mfma_f32_16x16x32_bf16(a[mi], b[ni], acc[mi][ni], 0, 0, 0);
        }
        __syncthreads();
    }
#pragma unroll
    for (int mi = 0; mi < 2; ++mi)
#pragma unroll
        for (int ni = 0; ni < 2; ++ni)
#pragma unroll
            for (int r = 0; r < 4; ++r) {
                int row = m0 + wm + mi * 16 + kg * 4 + r, col = j0 + wn + ni * 16 + lc;
                C[(size_t)row * ldc + col] = acc[mi][ni][r];
            }
}

// ---------------- split-K reduces ----------------
__global__ void k_red8(const float* __restrict__ part, float* __restrict__ Cf,
                       short* __restrict__ Cbf) {
    int i = blockIdx.x * 256 + threadIdx.x;          // over NN2*256/4
    if (i < NN2 * 64) {
        const float4* p = (const float4*)part + i;
        float4 s = p[0];
#pragma unroll
        for (int z = 1; z < 8; ++z) {
            float4 v = p[(size_t)z * NN2 * 64];
            s.x += v.x; s.y += v.y; s.z += v.z; s.w += v.w;
        }
        ((float4*)Cf)[i] = s;
        int n = i >> 6, col = (i & 63) * 4;
        short4 s4;
        s4.x = f2bf(s.x); s4.y = f2bf(s.y); s4.z = f2bf(s.z); s4.w = f2bf(s.w);
        *(short4*)(Cbf + (size_t)n * 3072 + col) = s4;
    }
}
__global__ void k_red4(const float* __restrict__ part, float* __restrict__ Cf) {
    int i = blockIdx.x * 256 + threadIdx.x;          // over NN2*128/4
    if (i < NN2 * 32) {
        const float4* p = (const float4*)part + i;
        float4 s = p[0];
#pragma unroll
        for (int z = 1; z < 4; ++z) {
            float4 v = p[(size_t)z * NN2 * 32];
            s.x += v.x; s.y += v.y; s.z += v.z; s.w += v.w;
        }
        ((float4*)Cf)[i] = s;
    }
}

// ---------------- fc partial ----------------
__global__ __launch_bounds__(256) void k_fc(const float* __restrict__ y2, const float* __restrict__ b2,
                                            const float* __restrict__ fcw, float* __restrict__ logits) {
    int qc = blockIdx.x >> 4, ch = blockIdx.x & 15;
    int q = qc / NCLS, c = qc % NCLS;
    const float* yp = y2 + (size_t)q * 131072 + ch * 8192;
    const float* wp = fcw + (size_t)c * 131072 + ch * 8192;
    int t = threadIdx.x;
    float acc = 0.f;
#pragma unroll
    for (int it = 0; it < 8; ++it) {
        int o = it * 1024 + t * 4;
        float4 yv = *(const float4*)(yp + o);
        float4 wv = *(const float4*)(wp + o);
        float bg = b2[((ch * 8192 + o) >> 2) & 31];
        acc += (yv.x + bg) * wv.x + (yv.y + bg) * wv.y + (yv.z + bg) * wv.z + (yv.w + bg) * wv.w;
    }
#pragma unroll
    for (int o = 32; o; o >>= 1) acc += __shfl_down(acc, o, 64);
    __shared__ float red[4];
    if ((t & 63) == 0) red[t >> 6] = acc;
    __syncthreads();
    if (t == 0) atomicAdd(&logits[qc], red[0] + red[1] + red[2] + red[3]);
}

__global__ void k_lsm(const float* __restrict__ logits, const float* __restrict__ fcb,
                      float* __restrict__ out) {
    int q = threadIdx.x;
    if (q < NB) {
        float v[NCLS];
#pragma unroll
        for (int c = 0; c < NCLS; ++c) v[c] = logits[q * NCLS + c] + fcb[c];
        float m = -1e30f;
#pragma unroll
        for (int c = 0; c < NCLS; ++c) m = fmaxf(m, v[c]);
        float s = 0.f;
#pragma unroll
        for (int c = 0; c < NCLS; ++c) s += expf(v[c] - m);
        float lse = m + logf(s);
#pragma unroll
        for (int c = 0; c < NCLS; ++c) out[q * NCLS + c] = v[c] - lse;
    }
}

extern "C" void kernel_launch(void* const* d_in, const int* in_sizes, int n_in,
                              void* d_out, int out_size, void* d_ws, size_t ws_size,
                              hipStream_t stream) {
    const float* x    = (const float*)d_in[0];
    const int*   ei1  = (const int*)d_in[1];
    const float* ew1  = (const float*)d_in[2];
    const int*   ei2  = (const int*)d_in[3];
    const float* ew2  = (const float*)d_in[4];
    const float* bmap = (const float*)d_in[5];
    const float* W1   = (const float*)d_in[6];
    const float* b1   = (const float*)d_in[7];
    const float* W2   = (const float*)d_in[8];
    const float* b2   = (const float*)d_in[9];
    const float* fcw  = (const float*)d_in[10];
    const float* fcb  = (const float*)d_in[11];
    float* out = (float*)d_out;

    char* w = (char*)d_ws;
    size_t o = 0;
    auto alloc = [&](size_t bytes) {
        char* p = w + o;
        o += (bytes + 255) & ~(size_t)255;
        return p;
    };
    float* deg1  = (float*)alloc(NN1 * 4);
    float* deg2  = (float*)alloc(NN2 * 4);
    int*   cnt1  = (int*)alloc(NN1 * 4);
    int*   cnt2  = (int*)alloc(NN2 * 4);
    int*   offs1 = (int*)alloc((NN1 + 1) * 4);
    int*   offs2 = (int*)alloc((NN2 + 1) * 4);
    int*   cur1  = (int*)alloc(NN1 * 4);
    int*   cur2  = (int*)alloc(NN2 * 4);
    int*   csrc1 = (int*)alloc(EE1 * 4);
    float* cnrm1 = (float*)alloc(EE1 * 4);
    int*   csrc2 = (int*)alloc(EE2 * 4);
    float* cnrm2 = (float*)alloc(EE2 * 4);
    float* R1a = (float*)alloc(NN1 * 64 * 4);
    float* R1b = (float*)alloc(NN1 * 64 * 4);
    float* R1c = (float*)alloc(NN1 * 64 * 4);
    short* T1bf = (short*)alloc((size_t)NN1 * 768 * 2);
    float* y1  = (float*)alloc((size_t)NN1 * 256 * 4);
    float* R2a = (float*)alloc((size_t)NN2 * 256 * 4);
    float* R2b = (float*)alloc((size_t)NN2 * 256 * 4);
    float* R2c = (float*)alloc((size_t)NN2 * 256 * 4);
    short* T2bf = (short*)alloc((size_t)NN2 * 3072 * 2);
    float* y2  = (float*)alloc((size_t)NN2 * 128 * 4);
    short* W1p = (short*)alloc(256 * 768 * 2);
    short* W2p = (short*)alloc(128 * 3072 * 2);
    float* part8 = (float*)alloc((size_t)8 * NN2 * 256 * 4);   // 32 MB
    float* part4 = (float*)alloc((size_t)4 * NN2 * 128 * 4);   // 8 MB
    float* logits = (float*)alloc(256);

    // ---- CSR build ----
    hipMemsetAsync(deg1, 0, NN1 * 4, stream);
    hipMemsetAsync(deg2, 0, NN2 * 4, stream);
    hipMemsetAsync(cnt1, 0, NN1 * 4, stream);
    hipMemsetAsync(cnt2, 0, NN2 * 4, stream);
    hipMemsetAsync(logits, 0, 256, stream);
    k_deg_hist<<<EE1 / 256, 256, 0, stream>>>(ei1, ew1, deg1, cnt1, EE1);
    k_deg_hist<<<EE2 / 256, 256, 0, stream>>>(ei2, ew2, deg2, cnt2, EE2);
    k_scan<NN1><<<1, 1024, 0, stream>>>(cnt1, offs1, cur1);
    k_scan<NN2><<<1, 1024, 0, stream>>>(cnt2, offs2, cur2);
    k_fill<<<EE1 / 256, 256, 0, stream>>>(ei1, ew1, deg1, cur1, csrc1, cnrm1, EE1);
    k_fill<<<EE2 / 256, 256, 0, stream>>>(ei2, ew2, deg2, cur2, csrc2, cnrm2, EE2);

    // ---- weights ----
    k_w1p<<<(256 * 768) / 256, 256, 0, stream>>>(W1, W1p);
    k_w2p<<<(128 * 3072) / 256, 256, 0, stream>>>(W2, W2p);

    // ---- conv1: Cheb recursion ----
    k_build_h0<<<(NN1 * 64) / 256, 256, 0, stream>>>(x, R1a, T1bf);
    {
        float *Tm1 = R1a, *Tm2 = nullptr, *fr = R1b, *spare = R1c;
        for (int k = 1; k < KCH; ++k) {
            k_prop1<<<NN1, 64, 0, stream>>>(Tm1, k == 1 ? Tm1 : Tm2, fr,
                                            T1bf + k * 64, offs1, csrc1, cnrm1, k == 1 ? 1 : 0);
            float* nf = (k == 1) ? spare : Tm2;
            Tm2 = Tm1; Tm1 = fr; fr = nf;
        }
    }
    // y1 = T1bf @ W1p^T   (M=8192, N=256, K=768)
    {
        dim3 g(NN1 / 64, 256 / 64, 1);
        k_gemm<true, true, false><<<g, 256, 0, stream>>>(T1bf, 768, W1p, 768, nullptr,
                                                         y1, 256, 768, 0);
    }
    // bmap GEMM split-K x8: part8[z] = bmap @ relu(y1+b1) chunk
    {
        dim3 g(NN2 / 64, 256 / 64, 8);
        k_gemm<false, false, true><<<g, 256, 0, stream>>>(bmap, NN1, y1, 256, b1,
                                                          part8, 256, 1024, (size_t)NN2 * 256);
        k_red8<<<(NN2 * 64 + 255) / 256, 256, 0, stream>>>(part8, R2a, T2bf);
    }
    // ---- conv2 ----
    {
        float *Tm1 = R2a, *Tm2 = nullptr, *fr = R2b, *spare = R2c;
        for (int k = 1; k < KCH; ++k) {
            k_prop2<<<NN2, 256, 0, stream>>>(Tm1, k == 1 ? Tm1 : Tm2, fr,
                                             T2bf + k * 256, offs2, csrc2, cnrm2, k == 1 ? 1 : 0);
            float* nf = (k == 1) ? spare : Tm2;
            Tm2 = Tm1; Tm1 = fr; fr = nf;
        }
    }
    // y2 = T2bf @ W2p^T   (M=4096, N=128, K=3072) split-K x4
    {
        dim3 g(NN2 / 64, 128 / 64, 4);
        k_gemm<true, true, false><<<g, 256, 0, stream>>>(T2bf, 3072, W2p, 3072, nullptr,
                                                         part4, 128, 768, (size_t)NN2 * 128);
        k_red4<<<(NN2 * 32 + 255) / 256, 256, 0, stream>>>(part4, y2);
    }

    // ---- fc + log_softmax ----
    k_fc<<<NB * NCLS * 16, 256, 0, stream>>>(y2, b2, fcw, logits);
    k_lsm<<<1, 64, 0, stream>>>(logits, fcb, out);
}

// Round 7
// 555.250 us; speedup vs baseline: 3.8698x; 1.1095x over previous
//
#include <hip/hip_runtime.h>

#define NB   4
#define NN1  8192
#define TT   15
#define NN2  4096
#define KCH  12
#define GG1  64
#define GG2  32
#define NCLS 6
#define EE1  131072
#define EE2  65536

typedef __attribute__((ext_vector_type(8))) short bf16x8;
typedef __attribute__((ext_vector_type(4))) float f32x4;

__device__ inline short f2bf(float f) {
    unsigned u = __builtin_bit_cast(unsigned, f);
    u += 0x7FFFu + ((u >> 16) & 1u);   // RNE
    return (short)(u >> 16);
}

// ---------------- degree + histogram ----------------
__global__ void k_deg_hist(const int* __restrict__ ei, const float* __restrict__ w,
                           float* __restrict__ deg, int* __restrict__ cnt, int E) {
    int e = blockIdx.x * 256 + threadIdx.x;
    if (e < E) {
        int d = ei[E + e];
        atomicAdd(&deg[d], w[e]);
        atomicAdd(&cnt[d], 1);
    }
}

// ---------------- exclusive scan (single block) ----------------
template <int N>
__global__ __launch_bounds__(1024) void k_scan(const int* __restrict__ cnt,
                                               int* __restrict__ offs, int* __restrict__ cur) {
    constexpr int PER = N / 1024;
    __shared__ int part[1024];
    int t = threadIdx.x;
    int loc[PER];
    int s = 0;
#pragma unroll
    for (int i = 0; i < PER; ++i) { loc[i] = s; s += cnt[t * PER + i]; }
    part[t] = s;
    __syncthreads();
    for (int off = 1; off < 1024; off <<= 1) {
        int v = (t >= off) ? part[t - off] : 0;
        __syncthreads();
        part[t] += v;
        __syncthreads();
    }
    int pre = t ? part[t - 1] : 0;
#pragma unroll
    for (int i = 0; i < PER; ++i) { int v = pre + loc[i]; offs[t * PER + i] = v; cur[t * PER + i] = v; }
    if (t == 1023) offs[N] = part[1023];
}

// ---------------- CSR fill (norm computed inline) ----------------
__global__ void k_fill(const int* __restrict__ ei, const float* __restrict__ w,
                       const float* __restrict__ deg, int* __restrict__ cur,
                       int* __restrict__ csrc, float* __restrict__ cnrm, int E) {
    int e = blockIdx.x * 256 + threadIdx.x;
    if (e < E) {
        int s = ei[e], d = ei[E + e];
        float ds = deg[s], dd = deg[d];
        float is = ds > 0.f ? 1.f / sqrtf(ds) : 0.f;
        float id = dd > 0.f ? 1.f / sqrtf(dd) : 0.f;
        int p = atomicAdd(&cur[d], 1);
        csrc[p] = s;
        cnrm[p] = -w[e] * is * id;
    }
}

// ---------------- build h0 (pads zeroed) ----------------
__global__ void k_build_h0(const float* __restrict__ x, float* __restrict__ h0,
                           short* __restrict__ bf0) {
    int idx = blockIdx.x * 256 + threadIdx.x;
    if (idx < NN1 * 64) {
        int n = idx >> 6, r = idx & 63;
        float v = 0.f;
        if (r < 60) {
            int t = r >> 2, b = r & 3;
            v = x[(b * NN1 + n) * TT + t];
        }
        h0[idx] = v;
        bf0[(size_t)n * 768 + r] = f2bf(v);
    }
}

// ---------------- conv1 prop: 1 wave/node, 4 edges in flight, float4 feats ----------------
__global__ __launch_bounds__(64) void k_prop1(const float* __restrict__ hprev,
                                              const float* __restrict__ hprev2,
                                              float* __restrict__ hout, short* __restrict__ bfs,
                                              const int* __restrict__ offs,
                                              const int* __restrict__ csrc,
                                              const float* __restrict__ cnrm, int first) {
    int n = blockIdx.x;
    int lane = threadIdx.x;
    int es = lane >> 4, f4 = lane & 15;
    int e0 = offs[n], e1 = offs[n + 1];
    f32x4 acc = {0.f, 0.f, 0.f, 0.f};
    for (int e = e0 + es; e < e1; e += 4) {
        int s = csrc[e];
        float wv = cnrm[e];
        const float4 v = *(const float4*)(hprev + (size_t)s * 64 + f4 * 4);
        acc[0] = fmaf(wv, v.x, acc[0]);
        acc[1] = fmaf(wv, v.y, acc[1]);
        acc[2] = fmaf(wv, v.z, acc[2]);
        acc[3] = fmaf(wv, v.w, acc[3]);
    }
#pragma unroll
    for (int i = 0; i < 4; ++i) {
        acc[i] += __shfl_xor(acc[i], 16, 64);
        acc[i] += __shfl_xor(acc[i], 32, 64);
    }
    if (es == 0) {
        float4 t;
        if (first) {
            t = make_float4(acc[0], acc[1], acc[2], acc[3]);
        } else {
            float4 p = *(const float4*)(hprev2 + (size_t)n * 64 + f4 * 4);
            t = make_float4(2.f * acc[0] - p.x, 2.f * acc[1] - p.y,
                            2.f * acc[2] - p.z, 2.f * acc[3] - p.w);
        }
        *(float4*)(hout + (size_t)n * 64 + f4 * 4) = t;
        short4 s4;
        s4.x = f2bf(t.x); s4.y = f2bf(t.y); s4.z = f2bf(t.z); s4.w = f2bf(t.w);
        *(short4*)(bfs + (size_t)n * 768 + f4 * 4) = s4;
    }
}

// ---------------- conv2 prop: 1 block(4 waves)/node, wave=edge slot, float4 feats ----------------
__global__ __launch_bounds__(256) void k_prop2(const float* __restrict__ hprev,
                                               const float* __restrict__ hprev2,
                                               float* __restrict__ hout, short* __restrict__ bfs,
                                               const int* __restrict__ offs,
                                               const int* __restrict__ csrc,
                                               const float* __restrict__ cnrm, int first) {
    __shared__ f32x4 red[3][64];
    int n = blockIdx.x;
    int t = threadIdx.x;
    int w = t >> 6, lane = t & 63;
    int e0 = offs[n], e1 = offs[n + 1];
    f32x4 acc = {0.f, 0.f, 0.f, 0.f};
    for (int e = e0 + w; e < e1; e += 4) {
        int s = csrc[e];
        float wv = cnrm[e];
        const float4 v = *(const float4*)(hprev + (size_t)s * 256 + lane * 4);
        acc[0] = fmaf(wv, v.x, acc[0]);
        acc[1] = fmaf(wv, v.y, acc[1]);
        acc[2] = fmaf(wv, v.z, acc[2]);
        acc[3] = fmaf(wv, v.w, acc[3]);
    }
    if (w) red[w - 1][lane] = acc;
    __syncthreads();
    if (w == 0) {
        f32x4 s = acc + red[0][lane] + red[1][lane] + red[2][lane];
        float4 tt;
        if (first) {
            tt = make_float4(s[0], s[1], s[2], s[3]);
        } else {
            float4 p = *(const float4*)(hprev2 + (size_t)n * 256 + lane * 4);
            tt = make_float4(2.f * s[0] - p.x, 2.f * s[1] - p.y,
                             2.f * s[2] - p.z, 2.f * s[3] - p.w);
        }
        *(float4*)(hout + (size_t)n * 256 + lane * 4) = tt;
        short4 s4;
        s4.x = f2bf(tt.x); s4.y = f2bf(tt.y); s4.z = f2bf(tt.z); s4.w = f2bf(tt.w);
        *(short4*)(bfs + (size_t)n * 3072 + lane * 4) = s4;
    }
}

// ---------------- block-diagonal weights, stored TRANSPOSED [N][K] bf16 ----------------
__global__ void k_w1p(const float* __restrict__ W1, short* __restrict__ W1p) {
    int idx = blockIdx.x * 256 + threadIdx.x;   // 256 * 768
    if (idx < 256 * 768) {
        int j = idx / 768, d = idx - j * 768;
        int g = j >> 2, b = j & 3;
        int k = d >> 6, r = d & 63, t = r >> 2, bp = r & 3;
        float v = (b == bp && t < TT) ? W1[k * (TT * GG1) + t * GG1 + g] : 0.f;
        W1p[idx] = f2bf(v);
    }
}
__global__ void k_w2p(const float* __restrict__ W2, short* __restrict__ W2p) {
    int idx = blockIdx.x * 256 + threadIdx.x;   // 128 * 3072
    if (idx < 128 * 3072) {
        int j = idx / 3072, d = idx - j * 3072;
        int g = j >> 2, b = j & 3;
        int k = d >> 8, r = d & 255, G = r >> 2, bp = r & 3;
        float v = (b == bp) ? W2[k * (GG1 * GG2) + G * GG2 + g] : 0.f;
        W2p[idx] = f2bf(v);
    }
}

// ---------------- unified MFMA GEMM, double-buffered, split-K ----------------
// A: fp32 or bf16 [M][lda]. B: bf16 [N][ldb] (j-major).
// Y1EPI: write yT[j][row] = f2bf(relu(acc + bias[j>>2])) (transposed bf16, ld=NN1)
template <bool A_BF, bool Y1EPI>
__global__ __launch_bounds__(256) void k_gemm(const void* __restrict__ Ap, int lda,
                                              const short* __restrict__ Bp, int ldb,
                                              const float* __restrict__ bias,
                                              float* __restrict__ Cf, int ldc,
                                              short* __restrict__ yT,
                                              int Kc, size_t pstride) {
    __shared__ short As[2][64][64];
    __shared__ short Bs[2][64][64];
    int m0 = blockIdx.x * 64, j0 = blockIdx.y * 64;
    int z = blockIdx.z;
    int kbeg = z * Kc;
    float* C = Cf + (size_t)z * pstride;
    int t = threadIdx.x;
    int lane = t & 63, wid = t >> 6;
    int wm = (wid >> 1) * 32, wn = (wid & 1) * 32;
    int lc = lane & 15, kg = lane >> 4;
    int r4 = t >> 2, c4 = (t & 3) * 16;
    int swa = (r4 & 7) << 3;

    const float* apf = (const float*)Ap + (size_t)(m0 + r4) * lda + kbeg + (t & 3) * 4;
    const short* apb = (const short*)Ap + (size_t)(m0 + r4) * lda + kbeg + c4;
    const short* bp  = Bp + (size_t)(j0 + r4) * ldb + kbeg + c4;

    float4 af0, af1, af2, af3;
    bf16x8 ab0, ab1, bb0, bb1;

    auto load_tile = [&](int k0) {
        if (A_BF) {
            ab0 = *(const bf16x8*)(apb + k0);
            ab1 = *(const bf16x8*)(apb + k0 + 8);
        } else {
            af0 = *(const float4*)(apf + k0);
            af1 = *(const float4*)(apf + k0 + 16);
            af2 = *(const float4*)(apf + k0 + 32);
            af3 = *(const float4*)(apf + k0 + 48);
        }
        bb0 = *(const bf16x8*)(bp + k0);
        bb1 = *(const bf16x8*)(bp + k0 + 8);
    };
    auto write_tile = [&](int buf) {
        if (A_BF) {
            *(bf16x8*)&As[buf][r4][c4 ^ swa] = ab0;
            *(bf16x8*)&As[buf][r4][(c4 + 8) ^ swa] = ab1;
        } else {
            short4 s;
            s.x = f2bf(af0.x); s.y = f2bf(af0.y); s.z = f2bf(af0.z); s.w = f2bf(af0.w);
            *(short4*)&As[buf][r4][((t & 3) * 4) ^ swa] = s;
            s.x = f2bf(af1.x); s.y = f2bf(af1.y); s.z = f2bf(af1.z); s.w = f2bf(af1.w);
            *(short4*)&As[buf][r4][((t & 3) * 4 + 16) ^ swa] = s;
            s.x = f2bf(af2.x); s.y = f2bf(af2.y); s.z = f2bf(af2.z); s.w = f2bf(af2.w);
            *(short4*)&As[buf][r4][((t & 3) * 4 + 32) ^ swa] = s;
            s.x = f2bf(af3.x); s.y = f2bf(af3.y); s.z = f2bf(af3.z); s.w = f2bf(af3.w);
            *(short4*)&As[buf][r4][((t & 3) * 4 + 48) ^ swa] = s;
        }
        *(bf16x8*)&Bs[buf][r4][c4 ^ swa] = bb0;
        *(bf16x8*)&Bs[buf][r4][(c4 + 8) ^ swa] = bb1;
    };

    f32x4 acc[2][2] = {};
    const int NIT = Kc >> 6;
    load_tile(0);
    write_tile(0);
    __syncthreads();
    for (int it = 0; it < NIT; ++it) {
        int cur = it & 1;
        if (it + 1 < NIT) load_tile((it + 1) << 6);   // issue early; waitcnt lands after MFMA
#pragma unroll
        for (int ks = 0; ks < 2; ++ks) {
            int kk = ks * 32 + kg * 8;
            bf16x8 a[2], b[2];
#pragma unroll
            for (int mi = 0; mi < 2; ++mi) {
                int row = wm + mi * 16 + lc;
                a[mi] = *(bf16x8*)&As[cur][row][kk ^ ((row & 7) << 3)];
            }
#pragma unroll
            for (int ni = 0; ni < 2; ++ni) {
                int row = wn + ni * 16 + lc;
                b[ni] = *(bf16x8*)&Bs[cur][row][kk ^ ((row & 7) << 3)];
            }
#pragma unroll
            for (int mi = 0; mi < 2; ++mi)
#pragma unroll
                for (int ni = 0; ni < 2; ++ni)
                    acc[mi][ni] = __builtin_amdgcn_mfma_f32_16x16x32_bf16(a[mi], b[ni], acc[mi][ni], 0, 0, 0);
        }
        if (it + 1 < NIT) write_tile(cur ^ 1);        // write-late (other buffer)
        __syncthreads();
    }

    if (Y1EPI) {
#pragma unroll
        for (int mi = 0; mi < 2; ++mi)
#pragma unroll
            for (int ni = 0; ni < 2; ++ni) {
                int col = j0 + wn + ni * 16 + lc;
                float bb = bias[col >> 2];
                int row = m0 + wm + mi * 16 + kg * 4;
                short4 s;
                s.x = f2bf(fmaxf(acc[mi][ni][0] + bb, 0.f));
                s.y = f2bf(fmaxf(acc[mi][ni][1] + bb, 0.f));
                s.z = f2bf(fmaxf(acc[mi][ni][2] + bb, 0.f));
                s.w = f2bf(fmaxf(acc[mi][ni][3] + bb, 0.f));
                *(short4*)(yT + (size_t)col * NN1 + row) = s;
            }
    } else {
#pragma unroll
        for (int mi = 0; mi < 2; ++mi)
#pragma unroll
            for (int ni = 0; ni < 2; ++ni)
#pragma unroll
                for (int r = 0; r < 4; ++r) {
                    int row = m0 + wm + mi * 16 + kg * 4 + r, col = j0 + wn + ni * 16 + lc;
                    C[(size_t)row * ldc + col] = acc[mi][ni][r];
                }
    }
}

// ---------------- split-K reduces ----------------
__global__ void k_red8(const float* __restrict__ part, float* __restrict__ Cf,
                       short* __restrict__ Cbf) {
    int i = blockIdx.x * 256 + threadIdx.x;          // over NN2*256/4
    if (i < NN2 * 64) {
        const float4* p = (const float4*)part + i;
        float4 s = p[0];
#pragma unroll
        for (int z = 1; z < 8; ++z) {
            float4 v = p[(size_t)z * NN2 * 64];
            s.x += v.x; s.y += v.y; s.z += v.z; s.w += v.w;
        }
        ((float4*)Cf)[i] = s;
        int n = i >> 6, col = (i & 63) * 4;
        short4 s4;
        s4.x = f2bf(s.x); s4.y = f2bf(s.y); s4.z = f2bf(s.z); s4.w = f2bf(s.w);
        *(short4*)(Cbf + (size_t)n * 3072 + col) = s4;
    }
}
__global__ void k_red4(const float* __restrict__ part, float* __restrict__ Cf) {
    int i = blockIdx.x * 256 + threadIdx.x;          // over NN2*128/4
    if (i < NN2 * 32) {
        const float4* p = (const float4*)part + i;
        float4 s = p[0];
#pragma unroll
        for (int z = 1; z < 4; ++z) {
            float4 v = p[(size_t)z * NN2 * 32];
            s.x += v.x; s.y += v.y; s.z += v.z; s.w += v.w;
        }
        ((float4*)Cf)[i] = s;
    }
}

// ---------------- fc partial ----------------
__global__ __launch_bounds__(256) void k_fc(const float* __restrict__ y2, const float* __restrict__ b2,
                                            const float* __restrict__ fcw, float* __restrict__ logits) {
    int qc = blockIdx.x >> 4, ch = blockIdx.x & 15;
    int q = qc / NCLS, c = qc % NCLS;
    const float* yp = y2 + (size_t)q * 131072 + ch * 8192;
    const float* wp = fcw + (size_t)c * 131072 + ch * 8192;
    int t = threadIdx.x;
    float acc = 0.f;
#pragma unroll
    for (int it = 0; it < 8; ++it) {
        int o = it * 1024 + t * 4;
        float4 yv = *(const float4*)(yp + o);
        float4 wv = *(const float4*)(wp + o);
        float bg = b2[((ch * 8192 + o) >> 2) & 31];
        acc += (yv.x + bg) * wv.x + (yv.y + bg) * wv.y + (yv.z + bg) * wv.z + (yv.w + bg) * wv.w;
    }
#pragma unroll
    for (int o = 32; o; o >>= 1) acc += __shfl_down(acc, o, 64);
    __shared__ float red[4];
    if ((t & 63) == 0) red[t >> 6] = acc;
    __syncthreads();
    if (t == 0) atomicAdd(&logits[qc], red[0] + red[1] + red[2] + red[3]);
}

__global__ void k_lsm(const float* __restrict__ logits, const float* __restrict__ fcb,
                      float* __restrict__ out) {
    int q = threadIdx.x;
    if (q < NB) {
        float v[NCLS];
#pragma unroll
        for (int c = 0; c < NCLS; ++c) v[c] = logits[q * NCLS + c] + fcb[c];
        float m = -1e30f;
#pragma unroll
        for (int c = 0; c < NCLS; ++c) m = fmaxf(m, v[c]);
        float s = 0.f;
#pragma unroll
        for (int c = 0; c < NCLS; ++c) s += expf(v[c] - m);
        float lse = m + logf(s);
#pragma unroll
        for (int c = 0; c < NCLS; ++c) out[q * NCLS + c] = v[c] - lse;
    }
}

extern "C" void kernel_launch(void* const* d_in, const int* in_sizes, int n_in,
                              void* d_out, int out_size, void* d_ws, size_t ws_size,
                              hipStream_t stream) {
    const float* x    = (const float*)d_in[0];
    const int*   ei1  = (const int*)d_in[1];
    const float* ew1  = (const float*)d_in[2];
    const int*   ei2  = (const int*)d_in[3];
    const float* ew2  = (const float*)d_in[4];
    const float* bmap = (const float*)d_in[5];
    const float* W1   = (const float*)d_in[6];
    const float* b1   = (const float*)d_in[7];
    const float* W2   = (const float*)d_in[8];
    const float* b2   = (const float*)d_in[9];
    const float* fcw  = (const float*)d_in[10];
    const float* fcb  = (const float*)d_in[11];
    float* out = (float*)d_out;

    char* w = (char*)d_ws;
    size_t o = 0;
    auto alloc = [&](size_t bytes) {
        char* p = w + o;
        o += (bytes + 255) & ~(size_t)255;
        return p;
    };
    float* deg1  = (float*)alloc(NN1 * 4);
    float* deg2  = (float*)alloc(NN2 * 4);
    int*   cnt1  = (int*)alloc(NN1 * 4);
    int*   cnt2  = (int*)alloc(NN2 * 4);
    int*   offs1 = (int*)alloc((NN1 + 1) * 4);
    int*   offs2 = (int*)alloc((NN2 + 1) * 4);
    int*   cur1  = (int*)alloc(NN1 * 4);
    int*   cur2  = (int*)alloc(NN2 * 4);
    int*   csrc1 = (int*)alloc(EE1 * 4);
    float* cnrm1 = (float*)alloc(EE1 * 4);
    int*   csrc2 = (int*)alloc(EE2 * 4);
    float* cnrm2 = (float*)alloc(EE2 * 4);
    float* R1a = (float*)alloc(NN1 * 64 * 4);
    float* R1b = (float*)alloc(NN1 * 64 * 4);
    float* R1c = (float*)alloc(NN1 * 64 * 4);
    short* T1bf = (short*)alloc((size_t)NN1 * 768 * 2);
    short* ybfT = (short*)alloc((size_t)256 * NN1 * 2);        // relu(y1+b1)^T bf16 [256][8192]
    float* R2a = (float*)alloc((size_t)NN2 * 256 * 4);
    float* R2b = (float*)alloc((size_t)NN2 * 256 * 4);
    float* R2c = (float*)alloc((size_t)NN2 * 256 * 4);
    short* T2bf = (short*)alloc((size_t)NN2 * 3072 * 2);
    float* y2  = (float*)alloc((size_t)NN2 * 128 * 4);
    short* W1p = (short*)alloc(256 * 768 * 2);
    short* W2p = (short*)alloc(128 * 3072 * 2);
    float* part8 = (float*)alloc((size_t)8 * NN2 * 256 * 4);   // 32 MB
    float* part4 = (float*)alloc((size_t)4 * NN2 * 128 * 4);   // 8 MB
    float* logits = (float*)alloc(256);

    // ---- CSR build ----
    hipMemsetAsync(deg1, 0, NN1 * 4, stream);
    hipMemsetAsync(deg2, 0, NN2 * 4, stream);
    hipMemsetAsync(cnt1, 0, NN1 * 4, stream);
    hipMemsetAsync(cnt2, 0, NN2 * 4, stream);
    hipMemsetAsync(logits, 0, 256, stream);
    k_deg_hist<<<EE1 / 256, 256, 0, stream>>>(ei1, ew1, deg1, cnt1, EE1);
    k_deg_hist<<<EE2 / 256, 256, 0, stream>>>(ei2, ew2, deg2, cnt2, EE2);
    k_scan<NN1><<<1, 1024, 0, stream>>>(cnt1, offs1, cur1);
    k_scan<NN2><<<1, 1024, 0, stream>>>(cnt2, offs2, cur2);
    k_fill<<<EE1 / 256, 256, 0, stream>>>(ei1, ew1, deg1, cur1, csrc1, cnrm1, EE1);
    k_fill<<<EE2 / 256, 256, 0, stream>>>(ei2, ew2, deg2, cur2, csrc2, cnrm2, EE2);

    // ---- weights ----
    k_w1p<<<(256 * 768) / 256, 256, 0, stream>>>(W1, W1p);
    k_w2p<<<(128 * 3072) / 256, 256, 0, stream>>>(W2, W2p);

    // ---- conv1: Cheb recursion ----
    k_build_h0<<<(NN1 * 64) / 256, 256, 0, stream>>>(x, R1a, T1bf);
    {
        float *Tm1 = R1a, *Tm2 = nullptr, *fr = R1b, *spare = R1c;
        for (int k = 1; k < KCH; ++k) {
            k_prop1<<<NN1, 64, 0, stream>>>(Tm1, k == 1 ? Tm1 : Tm2, fr,
                                            T1bf + k * 64, offs1, csrc1, cnrm1, k == 1 ? 1 : 0);
            float* nf = (k == 1) ? spare : Tm2;
            Tm2 = Tm1; Tm1 = fr; fr = nf;
        }
    }
    // ybfT = relu(T1bf @ W1p^T + b1)^T bf16   (M=8192, N=256, K=768)
    {
        dim3 g(NN1 / 64, 256 / 64, 1);
        k_gemm<true, true><<<g, 256, 0, stream>>>(T1bf, 768, W1p, 768, b1,
                                                  nullptr, 0, ybfT, 768, 0);
    }
    // bmap GEMM split-K x8: part8[z] = bmap @ ybfT^T chunk
    {
        dim3 g(NN2 / 64, 256 / 64, 8);
        k_gemm<false, false><<<g, 256, 0, stream>>>(bmap, NN1, ybfT, NN1, nullptr,
                                                    part8, 256, nullptr, 1024, (size_t)NN2 * 256);
        k_red8<<<(NN2 * 64 + 255) / 256, 256, 0, stream>>>(part8, R2a, T2bf);
    }
    // ---- conv2 ----
    {
        float *Tm1 = R2a, *Tm2 = nullptr, *fr = R2b, *spare = R2c;
        for (int k = 1; k < KCH; ++k) {
            k_prop2<<<NN2, 256, 0, stream>>>(Tm1, k == 1 ? Tm1 : Tm2, fr,
                                             T2bf + k * 256, offs2, csrc2, cnrm2, k == 1 ? 1 : 0);
            float* nf = (k == 1) ? spare : Tm2;
            Tm2 = Tm1; Tm1 = fr; fr = nf;
        }
    }
    // y2 = T2bf @ W2p^T   (M=4096, N=128, K=3072) split-K x4
    {
        dim3 g(NN2 / 64, 128 / 64, 4);
        k_gemm<true, false><<<g, 256, 0, stream>>>(T2bf, 3072, W2p, 3072, nullptr,
                                                   part4, 128, nullptr, 768, (size_t)NN2 * 128);
        k_red4<<<(NN2 * 32 + 255) / 256, 256, 0, stream>>>(part4, y2);
    }

    // ---- fc + log_softmax ----
    k_fc<<<NB * NCLS * 16, 256, 0, stream>>>(y2, b2, fcw, logits);
    k_lsm<<<1, 64, 0, stream>>>(logits, fcb, out);
}